// Round 2
// baseline (84.277 us; speedup 1.0000x reference)
//
#include <hip/hip_runtime.h>

// KspaceFillNeighbourLayer: temporal clipped box-filter sums (radii 0,1,2,4)
// over T=30 frames + masked blend.
// k,mask = (n,2,T,H,W) f32; out = (n,4,2,T,H,W) f32.
//
// One thread per 2 pixels (float2): load 30 k-frames into registers,
// pack the 30 mask bits (mask is exactly 0/1) into one uint per component.
// Mask window-sums = popcount(bits & compile-time range mask); k window-sums
// maintained incrementally (2 adds/step). Divide via v_rcp_f32 (1e-7 rel err
// vs 0.2975 threshold). Blend is an exact bit-select.
// Memory-bound: 126 MB read + 252 MB write.

#define T_FRAMES 30
constexpr int kP  = 256 * 256;      // H*W in floats
constexpr int kP2 = kP / 2;         // in float2

__global__ __launch_bounds__(256) void kfill_kernel(
    const float2* __restrict__ k, const float2* __restrict__ mask,
    float2* __restrict__ out, int total2)
{
    int tid = blockIdx.x * blockDim.x + threadIdx.x;
    if (tid >= total2) return;

    int col  = tid / kP2;           // col = n*2 + c  (compile-time pow2 -> shift)
    int pix  = tid - col * kP2;
    int nidx = col >> 1;
    int c    = col & 1;

    const size_t inBase = (size_t)col * T_FRAMES * kP2 + (size_t)pix;

    // Load all 30 k-frames (float2) and pack mask bits.
    float2 kv[T_FRAMES];
    unsigned bx = 0, by = 0;
#pragma unroll
    for (int t = 0; t < T_FRAMES; ++t) {
        kv[t] = k[inBase + (size_t)t * kP2];
        float2 m = mask[inBase + (size_t)t * kP2];
        bx |= ((unsigned)m.x) << t;   // m is exactly 0.0f or 1.0f
        by |= ((unsigned)m.y) << t;
    }

    const size_t outColBase = (size_t)(nidx * 8 + c) * T_FRAMES * kP2 + (size_t)pix;
    const int FD[4] = {0, 1, 2, 4};

#pragma unroll
    for (int f = 0; f < 4; ++f) {
        const int d = FD[f];
        float2* op = out + outColBase + (size_t)f * 2 * T_FRAMES * kP2;

        // k window sum for t=0: indices [0, d]
        float wkx = 0.0f, wky = 0.0f;
#pragma unroll
        for (int s = 0; s <= d; ++s) { wkx += kv[s].x; wky += kv[s].y; }

#pragma unroll
        for (int t = 0; t < T_FRAMES; ++t) {
            const int lo = (t - d < 0) ? 0 : t - d;
            const int hi = (t + d + 1 > T_FRAMES) ? T_FRAMES : t + d + 1;
            const unsigned rm = ((1u << hi) - 1) & ~((1u << lo) - 1);  // hi<=30<32

            float wmx = (float)__popc(bx & rm);
            float wmy = (float)__popc(by & rm);
            float rx = wkx * __builtin_amdgcn_rcpf(fmaxf(wmx, 1.0f));
            float ry = wky * __builtin_amdgcn_rcpf(fmaxf(wmy, 1.0f));

            float2 o;
            o.x = (bx & (1u << t)) ? kv[t].x : rx;
            o.y = (by & (1u << t)) ? kv[t].y : ry;
            op[(size_t)t * kP2] = o;

            // slide window t -> t+1: add (t+1)+d, drop t-d
            if (t + 1 < T_FRAMES) {
                if (t + 1 + d <= T_FRAMES - 1) { wkx += kv[t + 1 + d].x; wky += kv[t + 1 + d].y; }
                if (t - d >= 0)                { wkx -= kv[t - d].x;     wky -= kv[t - d].y;     }
            }
        }
    }
}

extern "C" void kernel_launch(void* const* d_in, const int* in_sizes, int n_in,
                              void* d_out, int out_size, void* d_ws, size_t ws_size,
                              hipStream_t stream) {
    const float2* k    = (const float2*)d_in[0];
    const float2* mask = (const float2*)d_in[1];
    float2* out = (float2*)d_out;

    const int ncol  = in_sizes[0] / (T_FRAMES * kP);  // n*2 = 8
    const int total2 = ncol * kP2;

    const int block = 256;
    const int grid = (total2 + block - 1) / block;
    kfill_kernel<<<grid, block, 0, stream>>>(k, mask, out, total2);
}